// Round 1
// baseline (300.640 us; speedup 1.0000x reference)
//
#include <hip/hip_runtime.h>
#include <hip/hip_bf16.h>
#include <stdint.h>

#define N_B   4
#define C_CH  256
#define MID   32
#define S_LEN 4096

typedef __attribute__((ext_vector_type(8))) short short8;
typedef __attribute__((ext_vector_type(4))) float f32x4;
typedef __attribute__((ext_vector_type(4))) unsigned int u32x4;

// ws layout (bytes)
#define OFF_QT_HI ((size_t)0)
#define OFF_QT_LO ((size_t)1 << 20)
#define OFF_KT_HI ((size_t)2 << 20)
#define OFF_KT_LO ((size_t)3 << 20)
#define OFF_VSW   ((size_t)4 << 20)   // [N][64 tiles][32768 B], swizzled

__device__ __forceinline__ unsigned short f2bf(float f) {
    __hip_bfloat16 h = __float2bfloat16(f);
    return *(unsigned short*)&h;
}

// ---------------- kernel 1a: Q^T / K^T hi+lo bf16, layout [N][S][32] ----------
__global__ __launch_bounds__(256) void qk_proj(
    const float* __restrict__ x, const float* __restrict__ Wq, const float* __restrict__ bq,
    const float* __restrict__ Wk, const float* __restrict__ bk,
    unsigned short* __restrict__ qt_hi, unsigned short* __restrict__ qt_lo,
    unsigned short* __restrict__ kt_hi, unsigned short* __restrict__ kt_lo)
{
    const int n = blockIdx.y;
    const int s = blockIdx.x * 256 + threadIdx.x;
    const float* W = blockIdx.z ? Wk : Wq;
    const float* b = blockIdx.z ? bk : bq;
    unsigned short* o_hi = blockIdx.z ? kt_hi : qt_hi;
    unsigned short* o_lo = blockIdx.z ? kt_lo : qt_lo;

    float acc[MID];
#pragma unroll
    for (int m = 0; m < MID; m++) acc[m] = b[m];

    const float* xp = x + ((size_t)n * C_CH) * S_LEN + s;
    for (int c = 0; c < C_CH; c++) {
        float xv = xp[(size_t)c * S_LEN];
#pragma unroll
        for (int m = 0; m < MID; m++) acc[m] = fmaf(W[m * C_CH + c], xv, acc[m]);
    }

    unsigned hi32[16], lo32[16];
#pragma unroll
    for (int m2 = 0; m2 < 16; m2++) {
        float f0 = acc[2 * m2], f1 = acc[2 * m2 + 1];
        unsigned short h0 = f2bf(f0), h1 = f2bf(f1);
        float fh0 = __bfloat162float(*(__hip_bfloat16*)&h0);
        float fh1 = __bfloat162float(*(__hip_bfloat16*)&h1);
        unsigned short l0 = f2bf(f0 - fh0), l1 = f2bf(f1 - fh1);
        hi32[m2] = (unsigned)h0 | ((unsigned)h1 << 16);
        lo32[m2] = (unsigned)l0 | ((unsigned)l1 << 16);
    }
    size_t row = ((size_t)n * S_LEN + s) * MID;   // in ushorts
#pragma unroll
    for (int j = 0; j < 4; j++) {
        u32x4 vh = { hi32[4*j], hi32[4*j+1], hi32[4*j+2], hi32[4*j+3] };
        u32x4 vl = { lo32[4*j], lo32[4*j+1], lo32[4*j+2], lo32[4*j+3] };
        *((u32x4*)(o_hi + row) + j) = vh;
        *((u32x4*)(o_lo + row) + j) = vl;
    }
}

// ---------------- kernel 1b: V bf16, pre-swizzled 32KB t-tile images ----------
__global__ __launch_bounds__(256) void v_proj(
    const float* __restrict__ x, const float* __restrict__ Wv, const float* __restrict__ bv,
    unsigned char* __restrict__ vsw)
{
    const int n  = blockIdx.y;
    const int tt = blockIdx.x;     // t tile (64 wide)
    const int t0 = tt * 64;
    const int tid = threadIdx.x;
    const int dg = tid >> 2;       // d base = dg*4
    const int tg = tid & 3;        // t sub-range = tg*16 .. +15

    __shared__ float xs[4][64];

    float acc[4][16];
#pragma unroll
    for (int j = 0; j < 4; j++) {
        float bj = bv[dg * 4 + j];
#pragma unroll
        for (int u = 0; u < 16; u++) acc[j][u] = bj;
    }

    for (int c0 = 0; c0 < C_CH; c0 += 4) {
        __syncthreads();
        xs[tid >> 6][tid & 63] =
            x[(((size_t)n * C_CH) + (c0 + (tid >> 6))) * S_LEN + t0 + (tid & 63)];
        f32x4 wr[4];
#pragma unroll
        for (int j = 0; j < 4; j++)
            wr[j] = *(const f32x4*)(Wv + (size_t)(dg * 4 + j) * C_CH + c0);
        __syncthreads();
#pragma unroll
        for (int cc = 0; cc < 4; cc++) {
            f32x4 xv[4];
#pragma unroll
            for (int q = 0; q < 4; q++) xv[q] = *(const f32x4*)(&xs[cc][tg * 16 + q * 4]);
#pragma unroll
            for (int j = 0; j < 4; j++) {
                float wj = wr[j][cc];
#pragma unroll
                for (int q = 0; q < 4; q++) {
                    acc[j][q*4+0] = fmaf(wj, xv[q][0], acc[j][q*4+0]);
                    acc[j][q*4+1] = fmaf(wj, xv[q][1], acc[j][q*4+1]);
                    acc[j][q*4+2] = fmaf(wj, xv[q][2], acc[j][q*4+2]);
                    acc[j][q*4+3] = fmaf(wj, xv[q][3], acc[j][q*4+3]);
                }
            }
        }
    }

    unsigned char* vb = vsw + ((size_t)(n * 64 + tt)) * 32768;
#pragma unroll
    for (int j = 0; j < 4; j++) {
        int d = dg * 4 + j;
        unsigned p32[8];
#pragma unroll
        for (int u2 = 0; u2 < 8; u2++)
            p32[u2] = (unsigned)f2bf(acc[j][2*u2]) | ((unsigned)f2bf(acc[j][2*u2+1]) << 16);
        int sw  = (d & 7) << 4;
        int tb0 = (tg * 32)      ^ sw;
        int tb1 = (tg * 32 + 16) ^ sw;
        u32x4 v0 = { p32[0], p32[1], p32[2], p32[3] };
        u32x4 v1 = { p32[4], p32[5], p32[6], p32[7] };
        *(u32x4*)(vb + d * 128 + tb0) = v0;
        *(u32x4*)(vb + d * 128 + tb1) = v1;
    }
}

// ---------------- kernel 2: fused flash attention + residual ------------------
__global__ __launch_bounds__(256) void attn(
    const unsigned short* __restrict__ qt_hi, const unsigned short* __restrict__ qt_lo,
    const unsigned short* __restrict__ kt_hi, const unsigned short* __restrict__ kt_lo,
    const unsigned char* __restrict__ vsw,
    const float* __restrict__ x, const float* __restrict__ gamma,
    float* __restrict__ out)
{
    const int n  = blockIdx.y;
    const int S0 = blockIdx.x * 64;
    const int tid = threadIdx.x;
    const int w   = tid >> 6;
    const int l   = tid & 63;
    const int l16 = l & 15, lq = l >> 4;

    __shared__ unsigned char  vlds[32768];
    __shared__ unsigned short plds[64 * 64];
    __shared__ float alds[64];
    __shared__ float llds[64];

    // Q A-fragments (rows S0 + w*16 + l16), hi/lo
    size_t qrow = ((size_t)n * S_LEN + S0 + w * 16 + l16) * MID + lq * 8;
    short8 qhi = *(const short8*)(qt_hi + qrow);
    short8 qlo = *(const short8*)(qt_lo + qrow);

    f32x4 acc[4][4];
#pragma unroll
    for (int a = 0; a < 4; a++)
#pragma unroll
        for (int b = 0; b < 4; b++) acc[a][b] = (f32x4){0.f, 0.f, 0.f, 0.f};
    float m_run[4] = { -__builtin_inff(), -__builtin_inff(), -__builtin_inff(), -__builtin_inff() };
    float l_run[4] = { 0.f, 0.f, 0.f, 0.f };

    const unsigned char* vtile = vsw + (size_t)n * 64 * 32768;

    for (int ti = 0; ti < 64; ti++) {
        const int t0 = ti * 64;
        __syncthreads();                       // previous iter done with LDS

        // V stage: issue global loads early (reg-staged, write-late)
        u32x4 vreg[8];
        const unsigned char* vb = vtile + (size_t)ti * 32768 + w * 8192 + l * 16;
#pragma unroll
        for (int j = 0; j < 8; j++) vreg[j] = *(const u32x4*)(vb + j * 1024);

        // QK^T: split-bf16 (hi*hi + hi*lo + lo*hi), fp32 accumulate
        f32x4 sD[4];
#pragma unroll
        for (int tf = 0; tf < 4; tf++) {
            size_t krow = ((size_t)n * S_LEN + t0 + tf * 16 + l16) * MID + lq * 8;
            short8 khi = *(const short8*)(kt_hi + krow);
            short8 klo = *(const short8*)(kt_lo + krow);
            f32x4 c0 = (f32x4){0.f, 0.f, 0.f, 0.f};
            c0 = __builtin_amdgcn_mfma_f32_16x16x32_bf16(qhi, khi, c0, 0, 0, 0);
            c0 = __builtin_amdgcn_mfma_f32_16x16x32_bf16(qhi, klo, c0, 0, 0, 0);
            c0 = __builtin_amdgcn_mfma_f32_16x16x32_bf16(qlo, khi, c0, 0, 0, 0);
            sD[tf] = c0;
        }

        // online softmax over this wave's 16 rows (row = w*16 + lq*4 + r)
        float alpha[4];
        unsigned short pbf[4][4];
#pragma unroll
        for (int r = 0; r < 4; r++) {
            float tmax = fmaxf(fmaxf(sD[0][r], sD[1][r]), fmaxf(sD[2][r], sD[3][r]));
            tmax = fmaxf(tmax, __shfl_xor(tmax, 1));
            tmax = fmaxf(tmax, __shfl_xor(tmax, 2));
            tmax = fmaxf(tmax, __shfl_xor(tmax, 4));
            tmax = fmaxf(tmax, __shfl_xor(tmax, 8));
            float mn = fmaxf(m_run[r], tmax);
            float al = __expf(m_run[r] - mn);    // exp(-inf)=0 on first tile
            float ps = 0.f;
#pragma unroll
            for (int tf = 0; tf < 4; tf++) {
                float p = __expf(sD[tf][r] - mn);
                ps += p;
                pbf[r][tf] = f2bf(p);
            }
            ps += __shfl_xor(ps, 1);
            ps += __shfl_xor(ps, 2);
            ps += __shfl_xor(ps, 4);
            ps += __shfl_xor(ps, 8);
            l_run[r] = al * l_run[r] + ps;
            m_run[r] = mn;
            alpha[r] = al;
        }

        // P -> LDS (XOR-swizzled rows)
#pragma unroll
        for (int r = 0; r < 4; r++) {
            int row = w * 16 + lq * 4 + r;
            int swz = ((row >> 2) & 3) << 5;
#pragma unroll
            for (int tf = 0; tf < 4; tf++) {
                int cb = ((tf * 16 + l16) * 2) ^ swz;
                *(unsigned short*)((unsigned char*)plds + row * 128 + cb) = pbf[r][tf];
            }
        }
        if (l16 == 0)
            *(f32x4*)(alds + w * 16 + lq * 4) = (f32x4){alpha[0], alpha[1], alpha[2], alpha[3]};

        // V regs -> LDS (compiler inserts vmcnt wait)
        {
            unsigned char* lb = vlds + w * 8192 + l * 16;
#pragma unroll
            for (int j = 0; j < 8; j++) *(u32x4*)(lb + j * 1024) = vreg[j];
        }
        __syncthreads();

        // rescale accumulators by alpha of their rows
#pragma unroll
        for (int sf = 0; sf < 4; sf++) {
            f32x4 av = *(const f32x4*)(alds + sf * 16 + lq * 4);
#pragma unroll
            for (int df = 0; df < 4; df++) {
                acc[sf][df][0] *= av[0]; acc[sf][df][1] *= av[1];
                acc[sf][df][2] *= av[2]; acc[sf][df][3] *= av[3];
            }
        }

        // PV: out^T[s, d] += P[s,t] * V[d,t]
#pragma unroll
        for (int kk = 0; kk < 2; kk++) {
            short8 pa[4];
#pragma unroll
            for (int sf = 0; sf < 4; sf++) {
                int row = sf * 16 + l16;
                int swz = ((row >> 2) & 3) << 5;
                int cb  = (kk * 64 + lq * 16) ^ swz;
                pa[sf] = *(const short8*)((unsigned char*)plds + row * 128 + cb);
            }
#pragma unroll
            for (int df = 0; df < 4; df++) {
                int d  = w * 64 + df * 16 + l16;
                int tb = (kk * 64 + lq * 16) ^ ((d & 7) << 4);
                short8 bv = *(const short8*)(vlds + d * 128 + tb);
#pragma unroll
                for (int sf = 0; sf < 4; sf++)
                    acc[sf][df] = __builtin_amdgcn_mfma_f32_16x16x32_bf16(pa[sf], bv, acc[sf][df], 0, 0, 0);
            }
        }
    }

    __syncthreads();
    if (l16 == 0)
        *(f32x4*)(llds + w * 16 + lq * 4) = (f32x4){l_run[0], l_run[1], l_run[2], l_run[3]};
    __syncthreads();

    const float g = gamma[0];
#pragma unroll
    for (int sf = 0; sf < 4; sf++) {
        f32x4 lv = *(const f32x4*)(llds + sf * 16 + lq * 4);
#pragma unroll
        for (int df = 0; df < 4; df++) {
            int d = w * 64 + df * 16 + l16;
#pragma unroll
            for (int r = 0; r < 4; r++) {
                int s = S0 + sf * 16 + lq * 4 + r;
                size_t idx = ((size_t)n * C_CH + d) * S_LEN + s;
                out[idx] = x[idx] + g * (acc[sf][df][r] / lv[r]);
            }
        }
    }
}

extern "C" void kernel_launch(void* const* d_in, const int* in_sizes, int n_in,
                              void* d_out, int out_size, void* d_ws, size_t ws_size,
                              hipStream_t stream) {
    const float* x     = (const float*)d_in[0];
    const float* Wq    = (const float*)d_in[1];
    const float* bq    = (const float*)d_in[2];
    const float* Wk    = (const float*)d_in[3];
    const float* bk    = (const float*)d_in[4];
    const float* Wv    = (const float*)d_in[5];
    const float* bv    = (const float*)d_in[6];
    const float* gamma = (const float*)d_in[7];
    float* out = (float*)d_out;

    unsigned char* ws = (unsigned char*)d_ws;
    unsigned short* qt_hi = (unsigned short*)(ws + OFF_QT_HI);
    unsigned short* qt_lo = (unsigned short*)(ws + OFF_QT_LO);
    unsigned short* kt_hi = (unsigned short*)(ws + OFF_KT_HI);
    unsigned short* kt_lo = (unsigned short*)(ws + OFF_KT_LO);
    unsigned char*  vsw   = ws + OFF_VSW;

    qk_proj<<<dim3(16, 4, 2), dim3(256), 0, stream>>>(x, Wq, bq, Wk, bk,
                                                      qt_hi, qt_lo, kt_hi, kt_lo);
    v_proj<<<dim3(64, 4), dim3(256), 0, stream>>>(x, Wv, bv, vsw);
    attn<<<dim3(64, 4), dim3(256), 0, stream>>>(qt_hi, qt_lo, kt_hi, kt_lo, vsw,
                                                x, gamma, out);
}

// Round 2
// 224.828 us; speedup vs baseline: 1.3372x; 1.3372x over previous
//
#include <hip/hip_runtime.h>
#include <hip/hip_bf16.h>
#include <stdint.h>

#define N_B   4
#define C_CH  256
#define MID   32
#define S_LEN 4096

typedef __attribute__((ext_vector_type(8))) short short8;
typedef __attribute__((ext_vector_type(4))) float f32x4;
typedef __attribute__((ext_vector_type(2))) unsigned int u32x2;
typedef __attribute__((ext_vector_type(4))) unsigned int u32x4;

// workspace layout (bytes)
#define OFF_XBF   ((size_t)0)                        // [4][4096][256] bf16 = 8 MB (x^T hi)
#define OFF_V     (OFF_XBF + (size_t)(8*1024*1024))  // [4][256][4096] bf16 = 8 MB
#define OFF_QT_HI (OFF_V + (size_t)(8*1024*1024))    // [4][4096][32] bf16 = 1 MB
#define OFF_QT_LO (OFF_QT_HI + (size_t)(1024*1024))
#define OFF_KT_HI (OFF_QT_LO + (size_t)(1024*1024))  // swizzled tile images, 1 MB
#define OFF_KT_LO (OFF_KT_HI + (size_t)(1024*1024))
#define OFF_WVBF  (OFF_KT_LO + (size_t)(1024*1024))  // [256][256] bf16 = 128 KB
#define OFF_WQT   (OFF_WVBF + (size_t)(128*1024))    // [256][32] f32 = 32 KB
#define OFF_WKT   (OFF_WQT + (size_t)(32*1024))      // [256][32] f32 = 32 KB

__device__ __forceinline__ unsigned short f2bf(float f) {
    __hip_bfloat16 h = __float2bfloat16(f);
    return *(unsigned short*)&h;
}
__device__ __forceinline__ float bf2f(unsigned short u) {
    return __bfloat162float(*(__hip_bfloat16*)&u);
}

// ---------- prep: x [n][c][t] f32 -> xbf [n][t][c] bf16 (hi only) ----------
__global__ __launch_bounds__(256) void prep_xbf(const float* __restrict__ x,
                                                unsigned short* __restrict__ xbf)
{
    const int tt = blockIdx.x;         // t tile of 64
    const int cc = blockIdx.y;         // c chunk of 64
    const int n  = blockIdx.z;
    const int l  = threadIdx.x & 63;
    const int cw = threadIdx.x >> 6;   // 0..3
    const int t  = tt * 64 + l;
    const int c0 = cc * 64 + cw * 16;

    unsigned short v[16];
#pragma unroll
    for (int k = 0; k < 16; k++)
        v[k] = f2bf(x[((size_t)n * C_CH + c0 + k) * S_LEN + t]);

    unsigned p[8];
#pragma unroll
    for (int j = 0; j < 8; j++) p[j] = (unsigned)v[2*j] | ((unsigned)v[2*j+1] << 16);
    unsigned short* o = xbf + ((size_t)n * S_LEN + t) * C_CH + c0;
    u32x4 a = { p[0], p[1], p[2], p[3] };
    u32x4 b = { p[4], p[5], p[6], p[7] };
    *(u32x4*)(o)     = a;
    *(u32x4*)(o + 8) = b;
}

// ---------- wprep: Wv -> bf16; Wq/Wk -> transposed f32 [c][32] ----------
__global__ __launch_bounds__(256) void wprep(const float* __restrict__ Wq,
                                             const float* __restrict__ Wk,
                                             const float* __restrict__ Wv,
                                             unsigned short* __restrict__ wvbf,
                                             float* __restrict__ wqT,
                                             float* __restrict__ wkT)
{
    const int b = blockIdx.x;
    if (b < 64) {
        int i = b * 1024 + threadIdx.x * 4;
        f32x4 w = *(const f32x4*)(Wv + i);
        u32x2 pk;
        pk[0] = (unsigned)f2bf(w[0]) | ((unsigned)f2bf(w[1]) << 16);
        pk[1] = (unsigned)f2bf(w[2]) | ((unsigned)f2bf(w[3]) << 16);
        *(u32x2*)(wvbf + i) = pk;
    } else if (b == 64) {
        int c = threadIdx.x;
#pragma unroll
        for (int m = 0; m < 32; m++) wqT[c * 32 + m] = Wq[m * C_CH + c];
    } else {
        int c = threadIdx.x;
#pragma unroll
        for (int m = 0; m < 32; m++) wkT[c * 32 + m] = Wk[m * C_CH + c];
    }
}

// ---------- fused Q/K projection: fp32 VALU, m-split across 8 waves ----------
__global__ __launch_bounds__(512) void qk_proj(
    const float* __restrict__ x, const float* __restrict__ wqT, const float* __restrict__ wkT,
    const float* __restrict__ bq, const float* __restrict__ bk,
    unsigned short* __restrict__ qt_hi, unsigned short* __restrict__ qt_lo,
    unsigned char* __restrict__ kt_hi, unsigned char* __restrict__ kt_lo)
{
    const int n  = blockIdx.y;
    const int S0 = blockIdx.x * 64;
    const int w  = threadIdx.x >> 6;       // 0..7
    const int l  = threadIdx.x & 63;
    const int s  = S0 + l;
    const bool isK = (w >= 4);
    const int m0 = (w & 3) * 8;
    const float* WT   = isK ? wkT : wqT;
    const float* bias = isK ? bk : bq;

    float acc[8];
#pragma unroll
    for (int k = 0; k < 8; k++) acc[k] = bias[m0 + k];

    const float* xp = x + (size_t)n * C_CH * S_LEN + s;
#pragma unroll 4
    for (int c = 0; c < C_CH; c++) {
        float xv = xp[(size_t)c * S_LEN];
        f32x4 w0 = *(const f32x4*)(WT + c * 32 + m0);
        f32x4 w1 = *(const f32x4*)(WT + c * 32 + m0 + 4);
        acc[0] = fmaf(w0[0], xv, acc[0]);
        acc[1] = fmaf(w0[1], xv, acc[1]);
        acc[2] = fmaf(w0[2], xv, acc[2]);
        acc[3] = fmaf(w0[3], xv, acc[3]);
        acc[4] = fmaf(w1[0], xv, acc[4]);
        acc[5] = fmaf(w1[1], xv, acc[5]);
        acc[6] = fmaf(w1[2], xv, acc[6]);
        acc[7] = fmaf(w1[3], xv, acc[7]);
    }

    unsigned hv[4], lv[4];
#pragma unroll
    for (int k2 = 0; k2 < 4; k2++) {
        float f0 = acc[2*k2], f1 = acc[2*k2+1];
        unsigned short h0 = f2bf(f0), h1 = f2bf(f1);
        unsigned short l0 = f2bf(f0 - bf2f(h0)), l1 = f2bf(f1 - bf2f(h1));
        hv[k2] = (unsigned)h0 | ((unsigned)h1 << 16);
        lv[k2] = (unsigned)l0 | ((unsigned)l1 << 16);
    }
    u32x4 vh = { hv[0], hv[1], hv[2], hv[3] };
    u32x4 vl = { lv[0], lv[1], lv[2], lv[3] };

    if (!isK) {
        size_t o = ((size_t)n * S_LEN + s) * MID + m0;
        *(u32x4*)(qt_hi + o) = vh;
        *(u32x4*)(qt_lo + o) = vl;
    } else {
        // swizzled tile image: tile = s>>6, row r = s&63, unit jj = w-4
        const int tile = s >> 6, r = s & 63, jj = w - 4;
        size_t base = ((size_t)n * 64 + tile) * 4096;
        int boff = r * 64 + ((jj * 16) ^ (((r >> 2) & 3) << 4));
        *(u32x4*)(kt_hi + base + boff) = vh;
        *(u32x4*)(kt_lo + base + boff) = vl;
    }
}

// ---------- V projection: bf16 MFMA GEMM, V[n][d][t] ----------
__global__ __launch_bounds__(256) void v_gemm(
    const unsigned short* __restrict__ xbf, const unsigned short* __restrict__ wvbf,
    const float* __restrict__ bv, unsigned short* __restrict__ V)
{
    const int n  = blockIdx.y;
    const int t0 = blockIdx.x * 64;
    const int w  = threadIdx.x >> 6;
    const int l  = threadIdx.x & 63;
    const int l16 = l & 15, lq = l >> 4;

    f32x4 acc[16];
#pragma unroll
    for (int i = 0; i < 16; i++) acc[i] = (f32x4){0.f, 0.f, 0.f, 0.f};

    const unsigned short* xrow = xbf + ((size_t)n * S_LEN + t0 + w * 16 + l16) * C_CH;
#pragma unroll
    for (int kk = 0; kk < 8; kk++) {
        short8 a = *(const short8*)(xrow + kk * 32 + lq * 8);
#pragma unroll
        for (int df = 0; df < 16; df++) {
            short8 b = *(const short8*)(wvbf + (size_t)(df * 16 + l16) * C_CH + kk * 32 + lq * 8);
            acc[df] = __builtin_amdgcn_mfma_f32_16x16x32_bf16(a, b, acc[df], 0, 0, 0);
        }
    }

    const int tb = t0 + w * 16 + lq * 4;
#pragma unroll
    for (int df = 0; df < 16; df++) {
        int d = df * 16 + l16;
        float bvv = bv[d];
        u32x2 pk;
        pk[0] = (unsigned)f2bf(acc[df][0] + bvv) | ((unsigned)f2bf(acc[df][1] + bvv) << 16);
        pk[1] = (unsigned)f2bf(acc[df][2] + bvv) | ((unsigned)f2bf(acc[df][3] + bvv) << 16);
        *(u32x2*)(V + ((size_t)n * C_CH + d) * S_LEN + tb) = pk;
    }
}

// ---------- fused flash attention + residual ----------
__global__ __launch_bounds__(256) void attn(
    const unsigned short* __restrict__ qt_hi, const unsigned short* __restrict__ qt_lo,
    const unsigned char* __restrict__ kt_hi, const unsigned char* __restrict__ kt_lo,
    const unsigned short* __restrict__ V, const float* __restrict__ x,
    const float* __restrict__ gamma, float* __restrict__ out)
{
    const int n   = blockIdx.y;
    const int S0  = blockIdx.x * 32;
    const int tid = threadIdx.x;
    const int w   = tid >> 6, l = tid & 63;
    const int l16 = l & 15, lq = l >> 4;

    __shared__ unsigned char  klds[2][8192];   // [buf][hi 4KB | lo 4KB], swizzled image
    __shared__ unsigned short plds[32 * 64];   // P, XOR-swizzled rows of 128B
    __shared__ float alds[32];
    __shared__ float llds[32];

    // Q fragments (used by waves 0,1)
    size_t qoff = ((size_t)n * S_LEN + S0 + (w & 1) * 16 + l16) * MID + lq * 8;
    short8 qhi = *(const short8*)(qt_hi + qoff);
    short8 qlo = *(const short8*)(qt_lo + qoff);

    f32x4 acc[2][4];
#pragma unroll
    for (int a = 0; a < 2; a++)
#pragma unroll
        for (int b = 0; b < 4; b++) acc[a][b] = (f32x4){0.f, 0.f, 0.f, 0.f};
    float m_run[4] = { -__builtin_inff(), -__builtin_inff(), -__builtin_inff(), -__builtin_inff() };
    float l_run[4] = { 0.f, 0.f, 0.f, 0.f };

    const size_t ktile = (size_t)n * 64 * 4096;  // byte base of this n's K tile images
    // prologue: stage K tile 0
    {
        u32x4 kh = *(const u32x4*)(kt_hi + ktile + tid * 16);
        u32x4 kl = *(const u32x4*)(kt_lo + ktile + tid * 16);
        *(u32x4*)(&klds[0][tid * 16])        = kh;
        *(u32x4*)(&klds[0][4096 + tid * 16]) = kl;
    }
    int cur = 0;

    const unsigned short* Vb = V + (size_t)n * C_CH * S_LEN;

    for (int ti = 0; ti < 64; ti++) {
        __syncthreads();                                   // B1: klds[cur] ready, plds free
        const int t0 = ti * 64;

        // V fragments for this tile (direct global, consumed after B2)
        short8 vfr[8];
#pragma unroll
        for (int df = 0; df < 4; df++)
#pragma unroll
            for (int kk = 0; kk < 2; kk++)
                vfr[df * 2 + kk] = *(const short8*)(Vb + (size_t)(w * 64 + df * 16 + l16) * S_LEN
                                                   + t0 + kk * 32 + lq * 8);

        // next K tile -> regs (written to other LDS buffer after B2)
        u32x4 nkh, nkl;
        if (ti < 63) {
            size_t tb = ktile + (size_t)(ti + 1) * 4096;
            nkh = *(const u32x4*)(kt_hi + tb + tid * 16);
            nkl = *(const u32x4*)(kt_lo + tb + tid * 16);
        }

        if (w < 2) {
            // QK^T: split-bf16 (hi*hi + hi*lo + lo*hi)
            f32x4 sD[4];
#pragma unroll
            for (int tf = 0; tf < 4; tf++) {
                int row = tf * 16 + l16;
                int boff = row * 64 + ((lq * 16) ^ (((row >> 2) & 3) << 4));
                short8 khi = *(const short8*)(&klds[cur][boff]);
                short8 klo = *(const short8*)(&klds[cur][4096 + boff]);
                f32x4 c0 = (f32x4){0.f, 0.f, 0.f, 0.f};
                c0 = __builtin_amdgcn_mfma_f32_16x16x32_bf16(qhi, khi, c0, 0, 0, 0);
                c0 = __builtin_amdgcn_mfma_f32_16x16x32_bf16(qhi, klo, c0, 0, 0, 0);
                c0 = __builtin_amdgcn_mfma_f32_16x16x32_bf16(qlo, khi, c0, 0, 0, 0);
                sD[tf] = c0;
            }
            // online softmax, rows = w*16 + lq*4 + r
            float alpha[4];
            unsigned short pbf[4][4];
#pragma unroll
            for (int r = 0; r < 4; r++) {
                float tmax = fmaxf(fmaxf(sD[0][r], sD[1][r]), fmaxf(sD[2][r], sD[3][r]));
                tmax = fmaxf(tmax, __shfl_xor(tmax, 1));
                tmax = fmaxf(tmax, __shfl_xor(tmax, 2));
                tmax = fmaxf(tmax, __shfl_xor(tmax, 4));
                tmax = fmaxf(tmax, __shfl_xor(tmax, 8));
                float mn = fmaxf(m_run[r], tmax);
                float al = __expf(m_run[r] - mn);
                float ps = 0.f;
#pragma unroll
                for (int tf = 0; tf < 4; tf++) {
                    float p = __expf(sD[tf][r] - mn);
                    ps += p;
                    pbf[r][tf] = f2bf(p);
                }
                ps += __shfl_xor(ps, 1);
                ps += __shfl_xor(ps, 2);
                ps += __shfl_xor(ps, 4);
                ps += __shfl_xor(ps, 8);
                l_run[r] = al * l_run[r] + ps;
                m_run[r] = mn;
                alpha[r] = al;
            }
            // P -> LDS (swizzled)
#pragma unroll
            for (int r = 0; r < 4; r++) {
                int row = w * 16 + lq * 4 + r;
                int sw = (row & 7) << 4;
#pragma unroll
                for (int tf = 0; tf < 4; tf++) {
                    int cb = ((tf * 16 + l16) * 2) ^ sw;
                    *(unsigned short*)((unsigned char*)plds + row * 128 + cb) = pbf[r][tf];
                }
            }
            if (l16 == 0) {
                f32x4 av = { alpha[0], alpha[1], alpha[2], alpha[3] };
                *(f32x4*)(alds + w * 16 + lq * 4) = av;
            }
        }
        __syncthreads();                                   // B2: P ready

        // rescale accumulators
#pragma unroll
        for (int sf = 0; sf < 2; sf++) {
            f32x4 av = *(const f32x4*)(alds + sf * 16 + lq * 4);
#pragma unroll
            for (int df = 0; df < 4; df++) {
                acc[sf][df][0] *= av[0]; acc[sf][df][1] *= av[1];
                acc[sf][df][2] *= av[2]; acc[sf][df][3] *= av[3];
            }
        }
        // PV
#pragma unroll
        for (int kk = 0; kk < 2; kk++) {
            short8 pa[2];
#pragma unroll
            for (int sf = 0; sf < 2; sf++) {
                int row = sf * 16 + l16;
                int cb = (kk * 64 + lq * 16) ^ ((row & 7) << 4);
                pa[sf] = *(const short8*)((unsigned char*)plds + row * 128 + cb);
            }
#pragma unroll
            for (int df = 0; df < 4; df++)
#pragma unroll
                for (int sf = 0; sf < 2; sf++)
                    acc[sf][df] = __builtin_amdgcn_mfma_f32_16x16x32_bf16(pa[sf], vfr[df * 2 + kk],
                                                                          acc[sf][df], 0, 0, 0);
        }

        // stage next K tile into other buffer
        if (ti < 63) {
            *(u32x4*)(&klds[cur ^ 1][tid * 16])        = nkh;
            *(u32x4*)(&klds[cur ^ 1][4096 + tid * 16]) = nkl;
        }
        cur ^= 1;
    }

    __syncthreads();
    if (w < 2 && l16 == 0) {
        f32x4 lv = { l_run[0], l_run[1], l_run[2], l_run[3] };
        *(f32x4*)(llds + w * 16 + lq * 4) = lv;
    }
    __syncthreads();

    const float g = gamma[0];
#pragma unroll
    for (int sf = 0; sf < 2; sf++) {
        f32x4 lv = *(const f32x4*)(llds + sf * 16 + lq * 4);
        f32x4 rl = { 1.f / lv[0], 1.f / lv[1], 1.f / lv[2], 1.f / lv[3] };
#pragma unroll
        for (int df = 0; df < 4; df++) {
            int d = w * 64 + df * 16 + l16;
            size_t base = ((size_t)n * C_CH + d) * S_LEN + S0 + sf * 16 + lq * 4;
            f32x4 xr = *(const f32x4*)(x + base);
            f32x4 o;
            o[0] = xr[0] + g * acc[sf][df][0] * rl[0];
            o[1] = xr[1] + g * acc[sf][df][1] * rl[1];
            o[2] = xr[2] + g * acc[sf][df][2] * rl[2];
            o[3] = xr[3] + g * acc[sf][df][3] * rl[3];
            *(f32x4*)(out + base) = o;
        }
    }
}

extern "C" void kernel_launch(void* const* d_in, const int* in_sizes, int n_in,
                              void* d_out, int out_size, void* d_ws, size_t ws_size,
                              hipStream_t stream) {
    const float* x     = (const float*)d_in[0];
    const float* Wq    = (const float*)d_in[1];
    const float* bq    = (const float*)d_in[2];
    const float* Wk    = (const float*)d_in[3];
    const float* bk    = (const float*)d_in[4];
    const float* Wv    = (const float*)d_in[5];
    const float* bv    = (const float*)d_in[6];
    const float* gamma = (const float*)d_in[7];
    float* out = (float*)d_out;

    unsigned char* ws = (unsigned char*)d_ws;
    unsigned short* xbf   = (unsigned short*)(ws + OFF_XBF);
    unsigned short* V     = (unsigned short*)(ws + OFF_V);
    unsigned short* qt_hi = (unsigned short*)(ws + OFF_QT_HI);
    unsigned short* qt_lo = (unsigned short*)(ws + OFF_QT_LO);
    unsigned char*  kt_hi = ws + OFF_KT_HI;
    unsigned char*  kt_lo = ws + OFF_KT_LO;
    unsigned short* wvbf  = (unsigned short*)(ws + OFF_WVBF);
    float*          wqT   = (float*)(ws + OFF_WQT);
    float*          wkT   = (float*)(ws + OFF_WKT);

    prep_xbf<<<dim3(64, 4, 4), dim3(256), 0, stream>>>(x, xbf);
    wprep<<<dim3(66), dim3(256), 0, stream>>>(Wq, Wk, Wv, wvbf, wqT, wkT);
    qk_proj<<<dim3(64, 4), dim3(512), 0, stream>>>(x, wqT, wkT, bq, bk,
                                                   qt_hi, qt_lo, kt_hi, kt_lo);
    v_gemm<<<dim3(64, 4), dim3(256), 0, stream>>>(xbf, wvbf, bv, V);
    attn<<<dim3(128, 4), dim3(256), 0, stream>>>(qt_hi, qt_lo, kt_hi, kt_lo, V,
                                                 x, gamma, out);
}